// Round 17
// baseline (1175.110 us; speedup 1.0000x reference)
//
#include <hip/hip_runtime.h>

#define DEVFN static __device__ __forceinline__

typedef __attribute__((ext_vector_type(8))) short short8;
typedef __attribute__((ext_vector_type(4))) float f32x4;

// ---------- bf16 helpers (raw ushort storage) ----------
DEVFN unsigned short f2bf(float f) {
    union { float f; unsigned u; } a; a.f = f;
    unsigned u = a.u;
    unsigned r = (u + 0x7FFFu + ((u >> 16) & 1u)) >> 16;   // RNE
    return (unsigned short)r;
}
DEVFN float bf2f(unsigned short b) {
    union { unsigned u; float f; } a; a.u = ((unsigned)b) << 16;
    return a.f;
}
DEVFN float2 bfpair(unsigned v) {
    float2 r;
    union { unsigned u; float f; } a;
    a.u = (v & 0xFFFFu) << 16; r.x = a.f;
    a.u = v & 0xFFFF0000u;     r.y = a.f;
    return r;
}

// ---------- async global->LDS (16B per lane, wave-uniform LDS base) ----------
DEVFN void gload16(const void* g, void* lds) {
    __builtin_amdgcn_global_load_lds(
        (const __attribute__((address_space(1))) unsigned int*)g,
        (__attribute__((address_space(3))) unsigned int*)lds, 16, 0, 0);
}

#define BAR() __builtin_amdgcn_s_barrier()
#define VMCNT4() asm volatile("s_waitcnt vmcnt(4)" ::: "memory")
#define VMCNT0() asm volatile("s_waitcnt vmcnt(0)" ::: "memory")

// ---------- merged prep kernel bodies ----------
DEVFN void pack_xs_body(const float* __restrict__ x, const float* __restrict__ r,
                        unsigned short* __restrict__ xs, int blk) {
    int i = blk * 256 + threadIdx.x;
    int n  = i >> 10;
    int cw = i & 1023;
    const float* src = (cw < 512) ? (x + (size_t)n * 2048 + cw * 4)
                                  : (r + (size_t)n * 2048 + (cw - 512) * 4);
    float4 v = *(const float4*)src;
    ushort4 o;
    o.x = f2bf(v.x); o.y = f2bf(v.y); o.z = f2bf(v.z); o.w = f2bf(v.w);
    *(ushort4*)(xs + (size_t)n * 4096 + cw * 4) = o;
}

DEVFN void transpose_body(const float* __restrict__ in,
                          unsigned short* __restrict__ out,
                          int R, int Cc, int bx, int by) {
    __shared__ float tile[32][33];
    const int t  = threadIdx.x;
    const int r  = t >> 3;
    const int c4 = (t & 7) * 4;
    const int tr = by * 32, tc = bx * 32;
    float4 v = *(const float4*)(in + (size_t)(tr + r) * Cc + tc + c4);
    tile[r][c4 + 0] = v.x; tile[r][c4 + 1] = v.y;
    tile[r][c4 + 2] = v.z; tile[r][c4 + 3] = v.w;
    __syncthreads();
    const int orow = r, oc = c4;
    ushort4 o;
    o.x = f2bf(tile[oc + 0][orow]);
    o.y = f2bf(tile[oc + 1][orow]);
    o.z = f2bf(tile[oc + 2][orow]);
    o.w = f2bf(tile[oc + 3][orow]);
    *(ushort4*)(out + (size_t)(tc + orow) * R + tr + oc) = o;
}

DEVFN void cast_body(const float* __restrict__ in,
                     unsigned short* __restrict__ out, int blk) {
    int i = blk * 1024 + threadIdx.x * 4;
    float4 v = *(const float4*)(in + i);
    ushort4 o;
    o.x = f2bf(v.x); o.y = f2bf(v.y); o.z = f2bf(v.z); o.w = f2bf(v.w);
    *(ushort4*)(out + i) = o;
}

// one launch: pack_xs(16384) + WbT(65536) + 5 transposes(5*4096) + Wk cast(4096)
__global__ __launch_bounds__(256) void prep_kernel(
        const float* __restrict__ x, const float* __restrict__ rwkv,
        unsigned short* __restrict__ xs,
        const float* __restrict__ Wb, unsigned short* __restrict__ wbT,
        const float* __restrict__ i0, const float* __restrict__ i1,
        const float* __restrict__ i2, const float* __restrict__ i3,
        const float* __restrict__ i4,
        unsigned short* __restrict__ o0, unsigned short* __restrict__ o1,
        unsigned short* __restrict__ o2, unsigned short* __restrict__ o3,
        unsigned short* __restrict__ o4,
        const float* __restrict__ Wk, unsigned short* __restrict__ wkC) {
    int b = blockIdx.x;
    if (b < 16384) { pack_xs_body(x, rwkv, xs, b); return; }
    b -= 16384;
    if (b < 65536) { transpose_body(Wb, wbT, 4096, 16384, b & 511, b >> 9); return; }
    b -= 65536;
    const int z = b >> 12, rem = b & 4095;
    if (z == 5) { cast_body(Wk, wkC, rem); return; }
    const float* in; unsigned short* out;
    switch (z) {
        case 0: in = i0; out = o0; break;
        case 1: in = i1; out = o1; break;
        case 2: in = i2; out = o2; break;
        case 3: in = i3; out = o3; break;
        default: in = i4; out = o4; break;
    }
    transpose_body(in, out, 2048, 2048, rem & 63, rem >> 6);
}

// ============================================================================
// 256x256 GEMM, 4-phase schedule (frozen R14 core). EPI:
//  0 = bf16 store (col split); 4 = split plain|sigmoid; 5 = tail merge.
// ============================================================================
template <int EPI>
__global__ __launch_bounds__(512, 2) void gemm256(
        const unsigned short* __restrict__ A, int lda,
        const unsigned short* __restrict__ Bt, int ldb,
        void* __restrict__ Cptr, void* __restrict__ Cptr2,
        int ldc, int splitcol, int K, int Mtiles,
        const float* __restrict__ aux_f32,
        const unsigned short* __restrict__ aux_bf16,
        float* __restrict__ loss_accum,
        const unsigned short* __restrict__ A2,
        const unsigned short* __restrict__ Bt2) {
    extern __shared__ char smem[];   // 131072 B
    const int tid  = threadIdx.x;
    const int wid  = tid >> 6, lane = tid & 63;
    const int wm   = wid >> 2, wn = wid & 3;
    const int l15  = lane & 15;
    const int lhi  = (lane >> 4) * 16;
    const int nkt  = K >> 6;

    int bid = blockIdx.x;
    bool sub1 = false;
    if constexpr (EPI == 5) {
        const int half = gridDim.x >> 1;
        if (bid >= half) { sub1 = true; bid -= half; A = A2; Bt = Bt2; }
    }

    // banded XCD mapping
    const int bandH = Mtiles >> 3;
    const int xcd = bid & 7, idx = bid >> 3;
    const int brow = (xcd * bandH + (idx % bandH)) << 8;
    const int bcol = (idx / bandH) << 8;

    const int lin0 = (wid * 2 + 0) * 1024 + lane * 16;
    const int lin1 = (wid * 2 + 1) * 1024 + lane * 16;
    const int ph0 = lin0 ^ (((lin0 >> 7) & 7) << 4);
    const int ph1v = lin1 ^ (((lin1 >> 7) & 7) << 4);
    const int srow0 = ph0 >> 7, scol0 = (ph0 & 127) >> 1;
    const int srow1 = ph1v >> 7, scol1 = (ph1v & 127) >> 1;
    const int dst0 = (wid * 2 + 0) * 1024;
    const int dst1 = (wid * 2 + 1) * 1024;

#define STAGE(t, mat, h_) do { \
        char* base_ = smem + (((t) & 1) * 65536) + ((mat) * 32768) + ((h_) * 16384); \
        const unsigned short* G_ = (mat) ? Bt : A; \
        const int ld_ = (mat) ? ldb : lda; \
        const int rb_ = ((mat) ? bcol : brow) + (h_) * 128; \
        gload16(G_ + (size_t)(rb_ + srow0) * ld_ + (t) * 64 + scol0, base_ + dst0); \
        gload16(G_ + (size_t)(rb_ + srow1) * ld_ + (t) * 64 + scol1, base_ + dst1); \
    } while (0)
#define STAGE_G(t, mat, h_) do { if ((t) < nkt) STAGE(t, mat, h_); } while (0)

#define LDA_FRAG(dst, buf, m, kk) do { \
        int lin_ = ((m) * 16 + l15) * 128 + (kk) * 64 + lhi; \
        int ph_  = lin_ ^ (((lin_ >> 7) & 7) << 4); \
        dst = *(const short8*)(smem + (buf) * 65536 + wm * 16384 + ph_); \
    } while (0)
#define LDB_FRAG(dst, buf, n, kk) do { \
        int lin_ = ((wn & 1) * 64 + (n) * 16 + l15) * 128 + (kk) * 64 + lhi; \
        int ph_  = lin_ ^ (((lin_ >> 7) & 7) << 4); \
        dst = *(const short8*)(smem + (buf) * 65536 + 32768 + (wn >> 1) * 16384 + ph_); \
    } while (0)

    f32x4 acc[8][4] = {};
    short8 afr[8][2], bfr[4][2];

#define MFMA_Q(mq) do { \
        __builtin_amdgcn_s_setprio(1); \
        _Pragma("unroll") \
        for (int n_ = 0; n_ < 4; ++n_) { \
            acc[2*(mq)][n_]   = __builtin_amdgcn_mfma_f32_16x16x32_bf16(afr[2*(mq)][0],   bfr[n_][0], acc[2*(mq)][n_],   0,0,0); \
            acc[2*(mq)][n_]   = __builtin_amdgcn_mfma_f32_16x16x32_bf16(afr[2*(mq)][1],   bfr[n_][1], acc[2*(mq)][n_],   0,0,0); \
            acc[2*(mq)+1][n_] = __builtin_amdgcn_mfma_f32_16x16x32_bf16(afr[2*(mq)+1][0], bfr[n_][0], acc[2*(mq)+1][n_], 0,0,0); \
            acc[2*(mq)+1][n_] = __builtin_amdgcn_mfma_f32_16x16x32_bf16(afr[2*(mq)+1][1], bfr[n_][1], acc[2*(mq)+1][n_], 0,0,0); \
        } \
        __builtin_amdgcn_s_setprio(0); \
    } while (0)

#define READ_B(b) do { \
        _Pragma("unroll") \
        for (int n_ = 0; n_ < 4; ++n_) { LDB_FRAG(bfr[n_][0], b, n_, 0); LDB_FRAG(bfr[n_][1], b, n_, 1); } \
    } while (0)
#define READ_QA(b, mq) do { \
        LDA_FRAG(afr[2*(mq)][0],   b, 2*(mq),   0); LDA_FRAG(afr[2*(mq)][1],   b, 2*(mq),   1); \
        LDA_FRAG(afr[2*(mq)+1][0], b, 2*(mq)+1, 0); LDA_FRAG(afr[2*(mq)+1][1], b, 2*(mq)+1, 1); \
    } while (0)

    // ---- prologue: T0 full + T1.B (12 loads) ----
    STAGE(0, 1, 0); STAGE(0, 1, 1); STAGE(0, 0, 0); STAGE(0, 0, 1);
    STAGE_G(1, 1, 0); STAGE_G(1, 1, 1);
    VMCNT4();
    BAR();

    const int niter = nkt >> 1;
    for (int it = 0; it < niter; ++it) {
        const int t0 = it * 2, t1 = t0 + 1;
        const bool lastIt = (it == niter - 1);

        READ_B(0); READ_QA(0, 0); READ_QA(0, 1);
        STAGE_G(t1, 0, 0); STAGE_G(t1, 0, 1);
        BAR();
        MFMA_Q(0); MFMA_Q(1);
        READ_QA(0, 2); READ_QA(0, 3);
        STAGE_G(t0 + 2, 1, 0); STAGE_G(t0 + 2, 1, 1);
        if (lastIt) { VMCNT0(); } else { VMCNT4(); }
        BAR();
        MFMA_Q(2); MFMA_Q(3);
        READ_B(1); READ_QA(1, 0); READ_QA(1, 1);
        STAGE_G(t0 + 2, 0, 0); STAGE_G(t0 + 2, 0, 1);
        BAR();
        MFMA_Q(0); MFMA_Q(1);
        READ_QA(1, 2); READ_QA(1, 3);
        STAGE_G(t1 + 2, 1, 0); STAGE_G(t1 + 2, 1, 1);
        if (lastIt) { VMCNT0(); } else { VMCNT4(); }
        BAR();
        MFMA_Q(2); MFMA_Q(3);
    }

    const int rl = (lane >> 4) * 4;
    const int cl = lane & 15;
    const int row0 = brow + wm * 128;

    if constexpr (EPI == 5) {
        const int col0 = bcol + wn * 64;
        if (!sub1) {
            float lsum = 0.f;
#pragma unroll
            for (int m = 0; m < 8; m++)
#pragma unroll
                for (int n = 0; n < 4; n++)
#pragma unroll
                    for (int rg = 0; rg < 4; rg++) {
                        int gr = row0 + m * 16 + rl + rg;
                        int gc = col0 + n * 16 + cl;
                        float d = acc[m][n][rg] - aux_f32[(size_t)gr * ldc + gc];
                        lsum += d * d;
                    }
#pragma unroll
            for (int msk = 1; msk < 64; msk <<= 1)
                lsum += __shfl_xor(lsum, msk, 64);
            if (lane == 0) atomicAdd(loss_accum, lsum);
        } else {
#pragma unroll
            for (int m = 0; m < 8; m++)
#pragma unroll
                for (int n = 0; n < 4; n++)
#pragma unroll
                    for (int rg = 0; rg < 4; rg++) {
                        int gr = row0 + m * 16 + rl + rg;
                        int gc = col0 + n * 16 + cl;
                        size_t idxo = (size_t)gr * ldc + gc;
                        float gv = bf2f(aux_bf16[idxo]);
                        ((float*)Cptr)[idxo] = acc[m][n][rg] * gv;
                    }
        }
        return;
    }

    void* Ceff = Cptr;
    bool second = false;
    int bcol_l = bcol;
    if constexpr (EPI == 0 || EPI == 4) {
        if (bcol >= splitcol) { Ceff = Cptr2; bcol_l = bcol - splitcol; second = true; }
    }
    const int col0 = bcol_l + wn * 64;

#pragma unroll
    for (int m = 0; m < 8; m++)
#pragma unroll
        for (int n = 0; n < 4; n++)
#pragma unroll
            for (int rg = 0; rg < 4; rg++) {
                int gr = row0 + m * 16 + rl + rg;
                int gc = col0 + n * 16 + cl;
                size_t idxo = (size_t)gr * ldc + gc;
                if constexpr (EPI == 0) {
                    ((unsigned short*)Ceff)[idxo] = f2bf(acc[m][n][rg]);
                } else {  // EPI == 4
                    if (second) {
                        float t = acc[m][n][rg] + aux_f32[gc];
                        ((unsigned short*)Ceff)[idxo] = f2bf(1.f / (1.f + expf(-t)));
                    } else {
                        ((unsigned short*)Ceff)[idxo] = f2bf(acc[m][n][rg]);
                    }
                }
            }
#undef STAGE
#undef STAGE_G
#undef LDA_FRAG
#undef LDB_FRAG
#undef MFMA_Q
#undef READ_B
#undef READ_QA
}

// ============================================================================
// light per-head GEMM (48KB LDS, BM=256 BN=128, 8 waves 4m x 2n).
// MODE 0 (wv): attno[n, h*128+d] = w[h][n,:] @ wvT[h*128+d, :]; grid 16h x 16m.
// MODE 1 (qt): qt[h][n, c] = q[n, h*128+:] @ wkC[c, h*128+:]^T; K=128;
//              grid 16h x 16m x 16n (bid = h*256 + m*16 + n).
// ============================================================================
template <int MODE>
__global__ __launch_bounds__(512) void gemmhv_kernel(
        const unsigned short* __restrict__ Abase,
        const unsigned short* __restrict__ Bbase,
        unsigned short* __restrict__ qtA, unsigned short* __restrict__ qtB,
        unsigned short* __restrict__ attno) {
    __shared__ __align__(16) unsigned short Atile[256 * 64];
    __shared__ __align__(16) unsigned short Btile[128 * 64];
    const int tid = threadIdx.x, wid = tid >> 6, lane = tid & 63;
    const int wm = wid >> 1, wn = wid & 1;
    const int l15 = lane & 15, lhi = (lane >> 4) * 16;

    int h, mt, nt;
    if constexpr (MODE == 1) {
        h = blockIdx.x >> 8; mt = (blockIdx.x >> 4) & 15; nt = blockIdx.x & 15;
    } else {
        h = blockIdx.x >> 4; mt = blockIdx.x & 15; nt = 0;
    }
    unsigned short* chunk = (h < 8) ? qtA + (size_t)h * 8388608
                                    : qtB + (size_t)(h - 8) * 8388608;
    const unsigned short* A = (MODE == 1) ? Abase + h * 128 : chunk;
    const unsigned short* B = (MODE == 1) ? Bbase + h * 128
                                          : Bbase + (size_t)(h * 128) * 2048;
    const int brow = mt << 8;
    const int bcolB = nt << 7;            // B row base (output-col base)
    const int NKT = (MODE == 1) ? 2 : 32;

#define WVST(buf, c, kt, G, ld, rbase) do { \
        int linc = (c) * 8192 + wid * 1024 + lane * 16; \
        int phc = linc ^ (((linc >> 7) & 7) << 4); \
        gload16((G) + (size_t)((rbase) + (phc >> 7)) * (ld) + (kt) * 64 + ((phc & 127) >> 1), \
                (char*)(buf) + (c) * 8192 + wid * 1024); \
    } while (0)

    f32x4 acc[4][4] = {};
    for (int kt = 0; kt < NKT; ++kt) {
        WVST(Atile, 0, kt, A, 2048, brow); WVST(Atile, 1, kt, A, 2048, brow);
        WVST(Atile, 2, kt, A, 2048, brow); WVST(Atile, 3, kt, A, 2048, brow);
        WVST(Btile, 0, kt, B, 2048, bcolB); WVST(Btile, 1, kt, B, 2048, bcolB);
        VMCNT0();
        BAR();
        short8 af[4][2], bf[4][2];
#pragma unroll
        for (int m = 0; m < 4; ++m)
#pragma unroll
            for (int kk = 0; kk < 2; ++kk) {
                int lin = (wm * 64 + m * 16 + l15) * 128 + kk * 64 + lhi;
                int ph = lin ^ (((lin >> 7) & 7) << 4);
                af[m][kk] = *(const short8*)((char*)Atile + ph);
            }
#pragma unroll
        for (int nn = 0; nn < 4; ++nn)
#pragma unroll
            for (int kk = 0; kk < 2; ++kk) {
                int lin = (wn * 64 + nn * 16 + l15) * 128 + kk * 64 + lhi;
                int ph = lin ^ (((lin >> 7) & 7) << 4);
                bf[nn][kk] = *(const short8*)((char*)Btile + ph);
            }
        __builtin_amdgcn_s_setprio(1);
#pragma unroll
        for (int m = 0; m < 4; ++m)
#pragma unroll
            for (int nn = 0; nn < 4; ++nn) {
                acc[m][nn] = __builtin_amdgcn_mfma_f32_16x16x32_bf16(af[m][0], bf[nn][0], acc[m][nn], 0, 0, 0);
                acc[m][nn] = __builtin_amdgcn_mfma_f32_16x16x32_bf16(af[m][1], bf[nn][1], acc[m][nn], 0, 0, 0);
            }
        __builtin_amdgcn_s_setprio(0);
        BAR();   // all reads retired before next stage overwrites
    }
    const int rl = (lane >> 4) * 4, cl = lane & 15;
#pragma unroll
    for (int m = 0; m < 4; ++m)
#pragma unroll
        for (int nn = 0; nn < 4; ++nn)
#pragma unroll
            for (int rg = 0; rg < 4; ++rg) {
                int gr = brow + wm * 64 + m * 16 + rl + rg;
                int lc = wn * 64 + nn * 16 + cl;
                if constexpr (MODE == 1) {
                    chunk[(size_t)gr * 2048 + bcolB + lc] = f2bf(acc[m][nn][rg]);
                } else {
                    attno[(size_t)gr * 2048 + h * 128 + lc] = f2bf(acc[m][nn][rg]);
                }
            }
#undef WVST
}

// ---------- attention v2 + fused pmean (R17: 2-head pairing, hoisted q) ----
__global__ __launch_bounds__(256) void attn2_kernel(
        const unsigned short* __restrict__ prefix,
        unsigned short* __restrict__ qtA, unsigned short* __restrict__ qtB,
        unsigned short* __restrict__ pmean) {
    __shared__ __align__(16) unsigned short pfx[8][2048];
    const int n = blockIdx.x, tid = threadIdx.x;
    const int wid = tid >> 6, lane = tid & 63;
#pragma unroll
    for (int r = 0; r < 8; ++r)
        *(uint4*)&pfx[r][tid * 8] =
            *(const uint4*)(prefix + (size_t)n * 16384 + r * 2048 + tid * 8);
    __syncthreads();

    // fused pmean: each thread owns cols [tid*8, tid*8+8)
    {
        float pacc[8] = {0, 0, 0, 0, 0, 0, 0, 0};
#pragma unroll
        for (int p = 0; p < 8; ++p) {
            uint4 pw = *(const uint4*)&pfx[p][tid * 8];
            const unsigned w_[4] = {pw.x, pw.y, pw.z, pw.w};
#pragma unroll
            for (int j = 0; j < 4; ++j) {
                float2 f = bfpair(w_[j]);
                pacc[2 * j] += f.x; pacc[2 * j + 1] += f.y;
            }
        }
        uint4 o;
        unsigned* ow = (unsigned*)&o;
#pragma unroll
        for (int j = 0; j < 4; ++j)
            ow[j] = (unsigned)f2bf(pacc[2 * j] * 0.125f) |
                    ((unsigned)f2bf(pacc[2 * j + 1] * 0.125f) << 16);
        *(uint4*)(pmean + (size_t)n * 2048 + tid * 8) = o;
    }

#pragma unroll
    for (int hp = 0; hp < 2; ++hp) {   // 2 heads per pass
        const int h0 = wid * 4 + hp * 2;
        unsigned short* qrow0 = ((h0 < 8) ? qtA + (size_t)h0 * 8388608
                                          : qtB + (size_t)(h0 - 8) * 8388608)
                                + (size_t)n * 2048;
        unsigned short* qrow1 = ((h0 + 1 < 8) ? qtA + (size_t)(h0 + 1) * 8388608
                                              : qtB + (size_t)(h0 - 7) * 8388608)
                                + (size_t)n * 2048;
        // hoist q conversion: 32 floats per head
        float qf0[32], qf1[32];
#pragma unroll
        for (int k = 0; k < 4; ++k) {
            uint4 w0 = *(const uint4*)(qrow0 + lane * 8 + k * 512);
            uint4 w1 = *(const uint4*)(qrow1 + lane * 8 + k * 512);
            const unsigned a0[4] = {w0.x, w0.y, w0.z, w0.w};
            const unsigned a1[4] = {w1.x, w1.y, w1.z, w1.w};
#pragma unroll
            for (int j = 0; j < 4; ++j) {
                float2 f0 = bfpair(a0[j]), f1 = bfpair(a1[j]);
                qf0[k * 8 + 2 * j] = f0.x; qf0[k * 8 + 2 * j + 1] = f0.y;
                qf1[k * 8 + 2 * j] = f1.x; qf1[k * 8 + 2 * j + 1] = f1.y;
            }
        }
        float s0[8], s1[8];
#pragma unroll
        for (int p = 0; p < 8; ++p) {
            float dx0 = 0.f, dy0 = 0.f, dx1 = 0.f, dy1 = 0.f;
#pragma unroll
            for (int k = 0; k < 4; ++k) {
                uint4 pw = *(const uint4*)&pfx[p][lane * 8 + k * 512];
                const unsigned aw[4] = {pw.x, pw.y, pw.z, pw.w};
#pragma unroll
                for (int j = 0; j < 4; ++j) {
                    float2 f = bfpair(aw[j]);
                    dx0 += f.x * qf0[k * 8 + 2 * j]; dy0 += f.y * qf0[k * 8 + 2 * j + 1];
                    dx1 += f.x * qf1[k * 8 + 2 * j]; dy1 += f.y * qf1[k * 8 + 2 * j + 1];
                }
            }
            float d0 = dx0 + dy0, d1 = dx1 + dy1;
#pragma unroll
            for (int msk = 1; msk < 64; msk <<= 1) {
                d0 += __shfl_xor(d0, msk, 64);
                d1 += __shfl_xor(d1, msk, 64);
            }
            s0[p] = d0 * 0.08838834764831845f;
            s1[p] = d1 * 0.08838834764831845f;
        }
        float mx0 = s0[0], mx1 = s1[0];
#pragma unroll
        for (int p = 1; p < 8; ++p) { mx0 = fmaxf(mx0, s0[p]); mx1 = fmaxf(mx1, s1[p]); }
        float a0[8], a1[8], den0 = 0.f, den1 = 0.f;
#pragma unroll
        for (int p = 0; p < 8; ++p) {
            a0[p] = expf(s0[p] - mx0); den0 += a0[p];
            a1[p] = expf(s1[p] - mx1); den1 += a1[p];
        }
        const float inv0 = 1.f / den0, inv1 = 1.f / den1;
#pragma unroll
        for (int p = 0; p < 8; ++p) { a0[p] *= inv0; a1[p] *= inv1; }
        // w phase: shared pv across the 2 heads
#pragma unroll
        for (int k = 0; k < 4; ++k) {
            float w0x[4] = {0, 0, 0, 0}, w0y[4] = {0, 0, 0, 0};
            float w1x[4] = {0, 0, 0, 0}, w1y[4] = {0, 0, 0, 0};
#pragma unroll
            for (int p = 0; p < 8; ++p) {
                uint4 pw = *(const uint4*)&pfx[p][lane * 8 + k * 512];
                const unsigned aw[4] = {pw.x, pw.y, pw.z, pw.w};
#pragma unroll
                for (int j = 0; j < 4; ++j) {
                    float2 f = bfpair(aw[j]);
                    w0x[j] += a0[p] * f.x; w0y[j] += a0[p] * f.y;
                    w1x[j] += a1[p] * f.x; w1y[j] += a1[p] * f.y;
                }
            }
            uint4 o0, o1;
            unsigned* p0 = (unsigned*)&o0;
            unsigned* p1 = (unsigned*)&o1;
#pragma unroll
            for (int j = 0; j < 4; ++j) {
                p0[j] = (unsigned)f2bf(w0x[j]) | ((unsigned)f2bf(w0y[j]) << 16);
                p1[j] = (unsigned)f2bf(w1x[j]) | ((unsigned)f2bf(w1y[j]) << 16);
            }
            *(uint4*)(qrow0 + lane * 8 + k * 512) = o0;
            *(uint4*)(qrow1 + lane * 8 + k * 512) = o1;
        }
    }
}

__global__ __launch_bounds__(64) void finalize_loss_kernel(
        const float* __restrict__ accum, float* __restrict__ dst) {
    if (threadIdx.x == 0) dst[0] = accum[0] * (1.0f / (4096.0f * 2048.0f));
}

// ---------- launch ----------
extern "C" void kernel_launch(void* const* d_in, const int* in_sizes, int n_in,
                              void* d_out, int out_size, void* d_ws, size_t ws_size,
                              hipStream_t stream) {
    const float* x    = (const float*)d_in[0];
    const float* rwkv = (const float*)d_in[1];
    const float* Wq   = (const float*)d_in[2];
    const float* Wk   = (const float*)d_in[3];
    const float* Wv   = (const float*)d_in[4];
    const float* Wo   = (const float*)d_in[5];
    const float* Wg   = (const float*)d_in[6];
    const float* bg   = (const float*)d_in[7];
    const float* Wb   = (const float*)d_in[8];
    const float* Wr   = (const float*)d_in[9];
    float* out = (float*)d_out;
    char*  ws  = (char*)d_ws;

    unsigned short* xs     = (unsigned short*)(ws + 0ull);
    unsigned short* wbT    = (unsigned short*)(ws + 33554432ull);    // dead after bridge
    unsigned short* qtA    = (unsigned short*)(ws + 33554432ull);    // 128MB (h 0-7)
    unsigned short* wqT    = (unsigned short*)(ws + 167772160ull);
    unsigned short* wgT    = (unsigned short*)(ws + 176160768ull);
    unsigned short* wkC    = (unsigned short*)(ws + 184549376ull);   // Wk cast (no T)
    unsigned short* wvT    = (unsigned short*)(ws + 192937984ull);
    unsigned short* wrT    = (unsigned short*)(ws + 201326592ull);
    unsigned short* woT    = (unsigned short*)(ws + 209715200ull);
    unsigned short* prefix = (unsigned short*)(ws + 218103808ull);   // 128MB
    unsigned short* qtB    = (unsigned short*)(ws + 352321536ull);   // 128MB (h 8-15)
    unsigned short* qbuf   = (unsigned short*)(ws + 486539264ull);
    unsigned short* gbuf   = (unsigned short*)(ws + 503316480ull);
    unsigned short* pmean  = (unsigned short*)(ws + 520093696ull);
    unsigned short* attno  = (unsigned short*)(ws + 536870912ull);
    float*          lossA  = (float*)(ws + 553648128ull);

    const int SMEM = 131072;
    const int BIG = 1 << 30;
    hipFuncSetAttribute(reinterpret_cast<const void*>(gemm256<0>),
                        hipFuncAttributeMaxDynamicSharedMemorySize, SMEM);
    hipFuncSetAttribute(reinterpret_cast<const void*>(gemm256<4>),
                        hipFuncAttributeMaxDynamicSharedMemorySize, SMEM);
    hipFuncSetAttribute(reinterpret_cast<const void*>(gemm256<5>),
                        hipFuncAttributeMaxDynamicSharedMemorySize, SMEM);

    hipMemsetAsync(lossA, 0, 16, stream);

    // prep: pack_xs + WbT + {Wq,Wg,Wv,Wr,Wo} transposes + Wk cast
    prep_kernel<<<106496, 256, 0, stream>>>(
        x, rwkv, xs, Wb, wbT,
        Wq, Wg, Wv, Wr, Wo, wqT, wgT, wvT, wrT, woT, Wk, wkC);

    // prefix = xs @ Wb          M=4096 N=16384 K=4096
    gemm256<0><<<dim3(1024), 512, SMEM, stream>>>(xs, 4096, wbT, 4096,
        prefix, nullptr, 16384, BIG, 4096, 16, nullptr, nullptr, nullptr,
        nullptr, nullptr);
    // [q|g] = x @ [Wq|Wg]       M=4096 N=4096 K=2048, split @2048
    gemm256<4><<<dim3(256), 512, SMEM, stream>>>(xs, 4096, wqT, 2048,
        qbuf, gbuf, 2048, 2048, 2048, 16, bg, nullptr, nullptr,
        nullptr, nullptr);
    // qt[h] = q_h @ Wk_h^T      light kernel, K=128, grid 16h x 16m x 16n
    gemmhv_kernel<1><<<4096, 512, 0, stream>>>(qbuf, wkC, qtA, qtB, nullptr);
    // attention + fused pmean: scores = qt.prefix, softmax, w in-place, pmean
    attn2_kernel<<<4096, 256, 0, stream>>>(prefix, qtA, qtB, pmean);
    // attno[n, hs] = w[h][n] @ Wv[:, hs]
    gemmhv_kernel<0><<<256, 512, 0, stream>>>(nullptr, wvT, qtA, qtB, attno);
    // TAIL: blocks 0-127: loss; blocks 128-255: out = (attno@Wo)*g
    gemm256<5><<<dim3(256), 512, SMEM, stream>>>(pmean, 2048, wrT, 2048,
        out, nullptr, 2048, BIG, 2048, 16, x, gbuf, lossA,
        attno, woT);

    finalize_loss_kernel<<<1, 64, 0, stream>>>(lossA, out + 8388608);
}

// Round 18
// 1077.160 us; speedup vs baseline: 1.0909x; 1.0909x over previous
//
#include <hip/hip_runtime.h>

#define DEVFN static __device__ __forceinline__

typedef __attribute__((ext_vector_type(8))) short short8;
typedef __attribute__((ext_vector_type(4))) float f32x4;

// ---------- bf16 helpers (raw ushort storage) ----------
DEVFN unsigned short f2bf(float f) {
    union { float f; unsigned u; } a; a.f = f;
    unsigned u = a.u;
    unsigned r = (u + 0x7FFFu + ((u >> 16) & 1u)) >> 16;   // RNE
    return (unsigned short)r;
}
DEVFN float bf2f(unsigned short b) {
    union { unsigned u; float f; } a; a.u = ((unsigned)b) << 16;
    return a.f;
}

// ---------- async global->LDS (16B per lane, wave-uniform LDS base) ----------
DEVFN void gload16(const void* g, void* lds) {
    __builtin_amdgcn_global_load_lds(
        (const __attribute__((address_space(1))) unsigned int*)g,
        (__attribute__((address_space(3))) unsigned int*)lds, 16, 0, 0);
}

#define BAR() __builtin_amdgcn_s_barrier()
#define VMCNT4() asm volatile("s_waitcnt vmcnt(4)" ::: "memory")
#define VMCNT0() asm volatile("s_waitcnt vmcnt(0)" ::: "memory")

// ---------- merged prep kernel bodies ----------
DEVFN void pack_xs_body(const float* __restrict__ x, const float* __restrict__ r,
                        unsigned short* __restrict__ xs, int blk) {
    int i = blk * 256 + threadIdx.x;
    int n  = i >> 10;
    int cw = i & 1023;
    const float* src = (cw < 512) ? (x + (size_t)n * 2048 + cw * 4)
                                  : (r + (size_t)n * 2048 + (cw - 512) * 4);
    float4 v = *(const float4*)src;
    ushort4 o;
    o.x = f2bf(v.x); o.y = f2bf(v.y); o.z = f2bf(v.z); o.w = f2bf(v.w);
    *(ushort4*)(xs + (size_t)n * 4096 + cw * 4) = o;
}

DEVFN void transpose_body(const float* __restrict__ in,
                          unsigned short* __restrict__ out,
                          int R, int Cc, int bx, int by) {
    __shared__ float tile[32][33];
    const int t  = threadIdx.x;
    const int r  = t >> 3;
    const int c4 = (t & 7) * 4;
    const int tr = by * 32, tc = bx * 32;
    float4 v = *(const float4*)(in + (size_t)(tr + r) * Cc + tc + c4);
    tile[r][c4 + 0] = v.x; tile[r][c4 + 1] = v.y;
    tile[r][c4 + 2] = v.z; tile[r][c4 + 3] = v.w;
    __syncthreads();
    const int orow = r, oc = c4;
    ushort4 o;
    o.x = f2bf(tile[oc + 0][orow]);
    o.y = f2bf(tile[oc + 1][orow]);
    o.z = f2bf(tile[oc + 2][orow]);
    o.w = f2bf(tile[oc + 3][orow]);
    *(ushort4*)(out + (size_t)(tc + orow) * R + tr + oc) = o;
}

DEVFN void cast_body(const float* __restrict__ in,
                     unsigned short* __restrict__ out, int blk) {
    int i = blk * 1024 + threadIdx.x * 4;
    float4 v = *(const float4*)(in + i);
    ushort4 o;
    o.x = f2bf(v.x); o.y = f2bf(v.y); o.z = f2bf(v.z); o.w = f2bf(v.w);
    *(ushort4*)(out + i) = o;
}

// one launch: pack_xs(16384) + WbT(65536) + 5 transposes(5*4096) + Wk cast(4096)
__global__ __launch_bounds__(256) void prep_kernel(
        const float* __restrict__ x, const float* __restrict__ rwkv,
        unsigned short* __restrict__ xs,
        const float* __restrict__ Wb, unsigned short* __restrict__ wbT,
        const float* __restrict__ i0, const float* __restrict__ i1,
        const float* __restrict__ i2, const float* __restrict__ i3,
        const float* __restrict__ i4,
        unsigned short* __restrict__ o0, unsigned short* __restrict__ o1,
        unsigned short* __restrict__ o2, unsigned short* __restrict__ o3,
        unsigned short* __restrict__ o4,
        const float* __restrict__ Wk, unsigned short* __restrict__ wkC) {
    int b = blockIdx.x;
    if (b < 16384) { pack_xs_body(x, rwkv, xs, b); return; }
    b -= 16384;
    if (b < 65536) { transpose_body(Wb, wbT, 4096, 16384, b & 511, b >> 9); return; }
    b -= 65536;
    const int z = b >> 12, rem = b & 4095;
    if (z == 5) { cast_body(Wk, wkC, rem); return; }
    const float* in; unsigned short* out;
    switch (z) {
        case 0: in = i0; out = o0; break;
        case 1: in = i1; out = o1; break;
        case 2: in = i2; out = o2; break;
        case 3: in = i3; out = o3; break;
        default: in = i4; out = o4; break;
    }
    transpose_body(in, out, 2048, 2048, rem & 63, rem >> 6);
}

// ============================================================================
// 256x256 GEMM, 4-phase schedule (frozen R14 core). EPI:
//  0 = bf16 store (col split); 4 = split plain|sigmoid; 5 = tail merge;
//  6 = qt mode: bid = (tile<<4)|h; A += h*128, Bt += h*128; C = per-h chunk.
// ============================================================================
template <int EPI>
__global__ __launch_bounds__(512, 2) void gemm256(
        const unsigned short* __restrict__ A, int lda,
        const unsigned short* __restrict__ Bt, int ldb,
        void* __restrict__ Cptr, void* __restrict__ Cptr2,
        int ldc, int splitcol, int K, int Mtiles,
        const float* __restrict__ aux_f32,
        const unsigned short* __restrict__ aux_bf16,
        float* __restrict__ loss_accum,
        const unsigned short* __restrict__ A2,
        const unsigned short* __restrict__ Bt2) {
    extern __shared__ char smem[];   // 131072 B
    const int tid  = threadIdx.x;
    const int wid  = tid >> 6, lane = tid & 63;
    const int wm   = wid >> 2, wn = wid & 3;
    const int l15  = lane & 15;
    const int lhi  = (lane >> 4) * 16;
    const int nkt  = K >> 6;

    int bid = blockIdx.x;
    bool sub1 = false;
    unsigned short* Cq = nullptr;
    if constexpr (EPI == 5) {
        const int half = gridDim.x >> 1;
        if (bid >= half) { sub1 = true; bid -= half; A = A2; Bt = Bt2; }
    }
    if constexpr (EPI == 6) {
        const int h = bid & 15; bid >>= 4;
        A  += h * 128;
        Bt += h * 128;
        Cq = (h < 8) ? (unsigned short*)Cptr  + (size_t)h * 8388608
                     : (unsigned short*)Cptr2 + (size_t)(h - 8) * 8388608;
    }

    // banded XCD mapping
    const int bandH = Mtiles >> 3;
    const int xcd = bid & 7, idx = bid >> 3;
    const int brow = (xcd * bandH + (idx % bandH)) << 8;
    const int bcol = (idx / bandH) << 8;

    const int lin0 = (wid * 2 + 0) * 1024 + lane * 16;
    const int lin1 = (wid * 2 + 1) * 1024 + lane * 16;
    const int ph0 = lin0 ^ (((lin0 >> 7) & 7) << 4);
    const int ph1v = lin1 ^ (((lin1 >> 7) & 7) << 4);
    const int srow0 = ph0 >> 7, scol0 = (ph0 & 127) >> 1;
    const int srow1 = ph1v >> 7, scol1 = (ph1v & 127) >> 1;
    const int dst0 = (wid * 2 + 0) * 1024;
    const int dst1 = (wid * 2 + 1) * 1024;

#define STAGE(t, mat, h_) do { \
        char* base_ = smem + (((t) & 1) * 65536) + ((mat) * 32768) + ((h_) * 16384); \
        const unsigned short* G_ = (mat) ? Bt : A; \
        const int ld_ = (mat) ? ldb : lda; \
        const int rb_ = ((mat) ? bcol : brow) + (h_) * 128; \
        gload16(G_ + (size_t)(rb_ + srow0) * ld_ + (t) * 64 + scol0, base_ + dst0); \
        gload16(G_ + (size_t)(rb_ + srow1) * ld_ + (t) * 64 + scol1, base_ + dst1); \
    } while (0)
#define STAGE_G(t, mat, h_) do { if ((t) < nkt) STAGE(t, mat, h_); } while (0)

#define LDA_FRAG(dst, buf, m, kk) do { \
        int lin_ = ((m) * 16 + l15) * 128 + (kk) * 64 + lhi; \
        int ph_  = lin_ ^ (((lin_ >> 7) & 7) << 4); \
        dst = *(const short8*)(smem + (buf) * 65536 + wm * 16384 + ph_); \
    } while (0)
#define LDB_FRAG(dst, buf, n, kk) do { \
        int lin_ = ((wn & 1) * 64 + (n) * 16 + l15) * 128 + (kk) * 64 + lhi; \
        int ph_  = lin_ ^ (((lin_ >> 7) & 7) << 4); \
        dst = *(const short8*)(smem + (buf) * 65536 + 32768 + (wn >> 1) * 16384 + ph_); \
    } while (0)

    f32x4 acc[8][4] = {};
    short8 afr[8][2], bfr[4][2];

#define MFMA_Q(mq) do { \
        __builtin_amdgcn_s_setprio(1); \
        _Pragma("unroll") \
        for (int n_ = 0; n_ < 4; ++n_) { \
            acc[2*(mq)][n_]   = __builtin_amdgcn_mfma_f32_16x16x32_bf16(afr[2*(mq)][0],   bfr[n_][0], acc[2*(mq)][n_],   0,0,0); \
            acc[2*(mq)][n_]   = __builtin_amdgcn_mfma_f32_16x16x32_bf16(afr[2*(mq)][1],   bfr[n_][1], acc[2*(mq)][n_],   0,0,0); \
            acc[2*(mq)+1][n_] = __builtin_amdgcn_mfma_f32_16x16x32_bf16(afr[2*(mq)+1][0], bfr[n_][0], acc[2*(mq)+1][n_], 0,0,0); \
            acc[2*(mq)+1][n_] = __builtin_amdgcn_mfma_f32_16x16x32_bf16(afr[2*(mq)+1][1], bfr[n_][1], acc[2*(mq)+1][n_], 0,0,0); \
        } \
        __builtin_amdgcn_s_setprio(0); \
    } while (0)

#define READ_B(b) do { \
        _Pragma("unroll") \
        for (int n_ = 0; n_ < 4; ++n_) { LDB_FRAG(bfr[n_][0], b, n_, 0); LDB_FRAG(bfr[n_][1], b, n_, 1); } \
    } while (0)
#define READ_QA(b, mq) do { \
        LDA_FRAG(afr[2*(mq)][0],   b, 2*(mq),   0); LDA_FRAG(afr[2*(mq)][1],   b, 2*(mq),   1); \
        LDA_FRAG(afr[2*(mq)+1][0], b, 2*(mq)+1, 0); LDA_FRAG(afr[2*(mq)+1][1], b, 2*(mq)+1, 1); \
    } while (0)

    // ---- prologue: T0 full + T1.B (12 loads) ----
    STAGE(0, 1, 0); STAGE(0, 1, 1); STAGE(0, 0, 0); STAGE(0, 0, 1);
    STAGE_G(1, 1, 0); STAGE_G(1, 1, 1);
    VMCNT4();
    BAR();

    const int niter = nkt >> 1;
    for (int it = 0; it < niter; ++it) {
        const int t0 = it * 2, t1 = t0 + 1;
        const bool lastIt = (it == niter - 1);

        READ_B(0); READ_QA(0, 0); READ_QA(0, 1);
        STAGE_G(t1, 0, 0); STAGE_G(t1, 0, 1);
        BAR();
        MFMA_Q(0); MFMA_Q(1);
        READ_QA(0, 2); READ_QA(0, 3);
        STAGE_G(t0 + 2, 1, 0); STAGE_G(t0 + 2, 1, 1);
        if (lastIt) { VMCNT0(); } else { VMCNT4(); }
        BAR();
        MFMA_Q(2); MFMA_Q(3);
        READ_B(1); READ_QA(1, 0); READ_QA(1, 1);
        STAGE_G(t0 + 2, 0, 0); STAGE_G(t0 + 2, 0, 1);
        BAR();
        MFMA_Q(0); MFMA_Q(1);
        READ_QA(1, 2); READ_QA(1, 3);
        STAGE_G(t1 + 2, 1, 0); STAGE_G(t1 + 2, 1, 1);
        if (lastIt) { VMCNT0(); } else { VMCNT4(); }
        BAR();
        MFMA_Q(2); MFMA_Q(3);
    }

    const int rl = (lane >> 4) * 4;
    const int cl = lane & 15;
    const int row0 = brow + wm * 128;

    if constexpr (EPI == 6) {
        const int col0 = bcol + wn * 64;
#pragma unroll
        for (int m = 0; m < 8; m++)
#pragma unroll
            for (int n = 0; n < 4; n++)
#pragma unroll
                for (int rg = 0; rg < 4; rg++) {
                    int gr = row0 + m * 16 + rl + rg;
                    int gc = col0 + n * 16 + cl;
                    Cq[(size_t)gr * 2048 + gc] = f2bf(acc[m][n][rg]);
                }
        return;
    }

    if constexpr (EPI == 5) {
        const int col0 = bcol + wn * 64;
        if (!sub1) {
            float lsum = 0.f;
#pragma unroll
            for (int m = 0; m < 8; m++)
#pragma unroll
                for (int n = 0; n < 4; n++)
#pragma unroll
                    for (int rg = 0; rg < 4; rg++) {
                        int gr = row0 + m * 16 + rl + rg;
                        int gc = col0 + n * 16 + cl;
                        float d = acc[m][n][rg] - aux_f32[(size_t)gr * ldc + gc];
                        lsum += d * d;
                    }
#pragma unroll
            for (int msk = 1; msk < 64; msk <<= 1)
                lsum += __shfl_xor(lsum, msk, 64);
            if (lane == 0) atomicAdd(loss_accum, lsum);
        } else {
#pragma unroll
            for (int m = 0; m < 8; m++)
#pragma unroll
                for (int n = 0; n < 4; n++)
#pragma unroll
                    for (int rg = 0; rg < 4; rg++) {
                        int gr = row0 + m * 16 + rl + rg;
                        int gc = col0 + n * 16 + cl;
                        size_t idxo = (size_t)gr * ldc + gc;
                        float gv = bf2f(aux_bf16[idxo]);
                        ((float*)Cptr)[idxo] = acc[m][n][rg] * gv;
                    }
        }
        return;
    }

    void* Ceff = Cptr;
    bool second = false;
    int bcol_l = bcol;
    if constexpr (EPI == 0 || EPI == 4) {
        if (bcol >= splitcol) { Ceff = Cptr2; bcol_l = bcol - splitcol; second = true; }
    }
    const int col0 = bcol_l + wn * 64;

#pragma unroll
    for (int m = 0; m < 8; m++)
#pragma unroll
        for (int n = 0; n < 4; n++)
#pragma unroll
            for (int rg = 0; rg < 4; rg++) {
                int gr = row0 + m * 16 + rl + rg;
                int gc = col0 + n * 16 + cl;
                size_t idxo = (size_t)gr * ldc + gc;
                if constexpr (EPI == 0) {
                    ((unsigned short*)Ceff)[idxo] = f2bf(acc[m][n][rg]);
                } else {  // EPI == 4
                    if (second) {
                        float t = acc[m][n][rg] + aux_f32[gc];
                        ((unsigned short*)Ceff)[idxo] = f2bf(1.f / (1.f + expf(-t)));
                    } else {
                        ((unsigned short*)Ceff)[idxo] = f2bf(acc[m][n][rg]);
                    }
                }
            }
#undef STAGE
#undef STAGE_G
#undef LDA_FRAG
#undef LDB_FRAG
#undef MFMA_Q
#undef READ_B
#undef READ_QA
}

// ---------- attention v2 + fused pmean (R16 exact) ----------
// block per n (256 thr = 4 waves, wave handles 4 h). prefix[n] in LDS (32KB).
__global__ __launch_bounds__(256) void attn2_kernel(
        const unsigned short* __restrict__ prefix,
        unsigned short* __restrict__ qtA, unsigned short* __restrict__ qtB,
        unsigned short* __restrict__ pmean) {
    __shared__ __align__(16) unsigned short pfx[8][2048];
    const int n = blockIdx.x, tid = threadIdx.x;
    const int wid = tid >> 6, lane = tid & 63;
#pragma unroll
    for (int r = 0; r < 8; ++r)
        *(uint4*)&pfx[r][tid * 8] =
            *(const uint4*)(prefix + (size_t)n * 16384 + r * 2048 + tid * 8);
    __syncthreads();

    // fused pmean: each thread owns cols [tid*8, tid*8+8)
    {
        float pacc[8] = {0, 0, 0, 0, 0, 0, 0, 0};
#pragma unroll
        for (int p = 0; p < 8; ++p) {
            short8 pv = *(const short8*)&pfx[p][tid * 8];
#pragma unroll
            for (int j = 0; j < 8; ++j)
                pacc[j] += bf2f((unsigned short)pv[j]);
        }
        uint4 o;
        unsigned* ow = (unsigned*)&o;
#pragma unroll
        for (int j = 0; j < 4; ++j)
            ow[j] = (unsigned)f2bf(pacc[2 * j] * 0.125f) |
                    ((unsigned)f2bf(pacc[2 * j + 1] * 0.125f) << 16);
        *(uint4*)(pmean + (size_t)n * 2048 + tid * 8) = o;
    }

#pragma unroll
    for (int hh = 0; hh < 4; ++hh) {
        const int h = wid * 4 + hh;
        unsigned short* qrow = ((h < 8) ? qtA + (size_t)h * 8388608
                                        : qtB + (size_t)(h - 8) * 8388608)
                               + (size_t)n * 2048;
        short8 qv[4];
#pragma unroll
        for (int k = 0; k < 4; ++k)
            qv[k] = *(const short8*)(qrow + lane * 8 + k * 512);
        float s[8];
#pragma unroll
        for (int p = 0; p < 8; ++p) {
            float d = 0.f;
#pragma unroll
            for (int k = 0; k < 4; ++k) {
                short8 pv = *(const short8*)&pfx[p][lane * 8 + k * 512];
#pragma unroll
                for (int j = 0; j < 8; ++j)
                    d += bf2f((unsigned short)qv[k][j]) * bf2f((unsigned short)pv[j]);
            }
#pragma unroll
            for (int msk = 1; msk < 64; msk <<= 1) d += __shfl_xor(d, msk, 64);
            s[p] = d * 0.08838834764831845f;   // 1/sqrt(128)
        }
        float mx = s[0];
#pragma unroll
        for (int p = 1; p < 8; ++p) mx = fmaxf(mx, s[p]);
        float e[8], den = 0.f;
#pragma unroll
        for (int p = 0; p < 8; ++p) { e[p] = expf(s[p] - mx); den += e[p]; }
        float inv = 1.f / den;
#pragma unroll
        for (int k = 0; k < 4; ++k) {
            float wa[8] = {0, 0, 0, 0, 0, 0, 0, 0};
#pragma unroll
            for (int p = 0; p < 8; ++p) {
                float a = e[p] * inv;
                short8 pv = *(const short8*)&pfx[p][lane * 8 + k * 512];
#pragma unroll
                for (int j = 0; j < 8; ++j)
                    wa[j] += a * bf2f((unsigned short)pv[j]);
            }
            short8 ov;
#pragma unroll
            for (int j = 0; j < 8; ++j) ov[j] = (short)f2bf(wa[j]);
            *(short8*)(qrow + lane * 8 + k * 512) = ov;   // w in-place over qt
        }
    }
}

// ---------- wv GEMM: attno[n, h*128+d] = w[h][n] @ WvT rows ---------
__global__ __launch_bounds__(512) void gemmwv_kernel(
        const unsigned short* __restrict__ qtA,
        const unsigned short* __restrict__ qtB,
        const unsigned short* __restrict__ wvT,
        unsigned short* __restrict__ attno) {
    __shared__ __align__(16) unsigned short Atile[256 * 64];
    __shared__ __align__(16) unsigned short Btile[128 * 64];
    const int tid = threadIdx.x, wid = tid >> 6, lane = tid & 63;
    const int wm = wid >> 1, wn = wid & 1;
    const int l15 = lane & 15, lhi = (lane >> 4) * 16;
    const int h = blockIdx.x >> 4, mt = blockIdx.x & 15;
    const unsigned short* A = (h < 8) ? qtA + (size_t)h * 8388608
                                      : qtB + (size_t)(h - 8) * 8388608;
    const unsigned short* B = wvT + (size_t)(h * 128) * 2048;
    const int brow = mt << 8;

#define WVST(buf, c, kt, G, ld, rbase) do { \
        int linc = (c) * 8192 + wid * 1024 + lane * 16; \
        int phc = linc ^ (((linc >> 7) & 7) << 4); \
        gload16((G) + (size_t)((rbase) + (phc >> 7)) * (ld) + (kt) * 64 + ((phc & 127) >> 1), \
                (char*)(buf) + (c) * 8192 + wid * 1024); \
    } while (0)

    f32x4 acc[4][4] = {};
    for (int kt = 0; kt < 32; ++kt) {
        WVST(Atile, 0, kt, A, 2048, brow); WVST(Atile, 1, kt, A, 2048, brow);
        WVST(Atile, 2, kt, A, 2048, brow); WVST(Atile, 3, kt, A, 2048, brow);
        WVST(Btile, 0, kt, B, 2048, 0);    WVST(Btile, 1, kt, B, 2048, 0);
        VMCNT0();
        BAR();
        short8 af[4][2], bf[4][2];
#pragma unroll
        for (int m = 0; m < 4; ++m)
#pragma unroll
            for (int kk = 0; kk < 2; ++kk) {
                int lin = (wm * 64 + m * 16 + l15) * 128 + kk * 64 + lhi;
                int ph = lin ^ (((lin >> 7) & 7) << 4);
                af[m][kk] = *(const short8*)((char*)Atile + ph);
            }
#pragma unroll
        for (int nn = 0; nn < 4; ++nn)
#pragma unroll
            for (int kk = 0; kk < 2; ++kk) {
                int lin = (wn * 64 + nn * 16 + l15) * 128 + kk * 64 + lhi;
                int ph = lin ^ (((lin >> 7) & 7) << 4);
                bf[nn][kk] = *(const short8*)((char*)Btile + ph);
            }
        __builtin_amdgcn_s_setprio(1);
#pragma unroll
        for (int m = 0; m < 4; ++m)
#pragma unroll
            for (int nn = 0; nn < 4; ++nn) {
                acc[m][nn] = __builtin_amdgcn_mfma_f32_16x16x32_bf16(af[m][0], bf[nn][0], acc[m][nn], 0, 0, 0);
                acc[m][nn] = __builtin_amdgcn_mfma_f32_16x16x32_bf16(af[m][1], bf[nn][1], acc[m][nn], 0, 0, 0);
            }
        __builtin_amdgcn_s_setprio(0);
        BAR();   // all reads retired before next stage overwrites
    }
    const int rl = (lane >> 4) * 4, cl = lane & 15;
#pragma unroll
    for (int m = 0; m < 4; ++m)
#pragma unroll
        for (int nn = 0; nn < 4; ++nn)
#pragma unroll
            for (int rg = 0; rg < 4; ++rg) {
                int gr = brow + wm * 64 + m * 16 + rl + rg;
                int gc = h * 128 + wn * 64 + nn * 16 + cl;
                attno[(size_t)gr * 2048 + gc] = f2bf(acc[m][nn][rg]);
            }
#undef WVST
}

__global__ __launch_bounds__(64) void finalize_loss_kernel(
        const float* __restrict__ accum, float* __restrict__ dst) {
    if (threadIdx.x == 0) dst[0] = accum[0] * (1.0f / (4096.0f * 2048.0f));
}

// ---------- launch ----------
extern "C" void kernel_launch(void* const* d_in, const int* in_sizes, int n_in,
                              void* d_out, int out_size, void* d_ws, size_t ws_size,
                              hipStream_t stream) {
    const float* x    = (const float*)d_in[0];
    const float* rwkv = (const float*)d_in[1];
    const float* Wq   = (const float*)d_in[2];
    const float* Wk   = (const float*)d_in[3];
    const float* Wv   = (const float*)d_in[4];
    const float* Wo   = (const float*)d_in[5];
    const float* Wg   = (const float*)d_in[6];
    const float* bg   = (const float*)d_in[7];
    const float* Wb   = (const float*)d_in[8];
    const float* Wr   = (const float*)d_in[9];
    float* out = (float*)d_out;
    char*  ws  = (char*)d_ws;

    unsigned short* xs     = (unsigned short*)(ws + 0ull);
    unsigned short* wbT    = (unsigned short*)(ws + 33554432ull);    // dead after bridge
    unsigned short* qtA    = (unsigned short*)(ws + 33554432ull);    // 128MB (h 0-7)
    unsigned short* wqT    = (unsigned short*)(ws + 167772160ull);
    unsigned short* wgT    = (unsigned short*)(ws + 176160768ull);
    unsigned short* wkC    = (unsigned short*)(ws + 184549376ull);   // Wk cast (no T)
    unsigned short* wvT    = (unsigned short*)(ws + 192937984ull);
    unsigned short* wrT    = (unsigned short*)(ws + 201326592ull);
    unsigned short* woT    = (unsigned short*)(ws + 209715200ull);
    unsigned short* prefix = (unsigned short*)(ws + 218103808ull);   // 128MB
    unsigned short* qtB    = (unsigned short*)(ws + 352321536ull);   // 128MB (h 8-15)
    unsigned short* qbuf   = (unsigned short*)(ws + 486539264ull);
    unsigned short* gbuf   = (unsigned short*)(ws + 503316480ull);
    unsigned short* pmean  = (unsigned short*)(ws + 520093696ull);
    unsigned short* attno  = (unsigned short*)(ws + 536870912ull);
    float*          lossA  = (float*)(ws + 553648128ull);

    const int SMEM = 131072;
    const int BIG = 1 << 30;
    hipFuncSetAttribute(reinterpret_cast<const void*>(gemm256<0>),
                        hipFuncAttributeMaxDynamicSharedMemorySize, SMEM);
    hipFuncSetAttribute(reinterpret_cast<const void*>(gemm256<4>),
                        hipFuncAttributeMaxDynamicSharedMemorySize, SMEM);
    hipFuncSetAttribute(reinterpret_cast<const void*>(gemm256<5>),
                        hipFuncAttributeMaxDynamicSharedMemorySize, SMEM);
    hipFuncSetAttribute(reinterpret_cast<const void*>(gemm256<6>),
                        hipFuncAttributeMaxDynamicSharedMemorySize, SMEM);

    hipMemsetAsync(lossA, 0, 16, stream);

    // prep: pack_xs + WbT + {Wq,Wg,Wv,Wr,Wo} transposes + Wk cast
    prep_kernel<<<106496, 256, 0, stream>>>(
        x, rwkv, xs, Wb, wbT,
        Wq, Wg, Wv, Wr, Wo, wqT, wgT, wvT, wrT, woT, Wk, wkC);

    // prefix = xs @ Wb          M=4096 N=16384 K=4096
    gemm256<0><<<dim3(1024), 512, SMEM, stream>>>(xs, 4096, wbT, 4096,
        prefix, nullptr, 16384, BIG, 4096, 16, nullptr, nullptr, nullptr,
        nullptr, nullptr);
    // [q|g] = x @ [Wq|Wg]       M=4096 N=4096 K=2048, split @2048
    gemm256<4><<<dim3(256), 512, SMEM, stream>>>(xs, 4096, wqT, 2048,
        qbuf, gbuf, 2048, 2048, 2048, 16, bg, nullptr, nullptr,
        nullptr, nullptr);
    // qt[h] = q_h @ Wk_h^T      per h: M=4096 N=2048 K=128
    gemm256<6><<<dim3(2048), 512, SMEM, stream>>>(qbuf, 2048, wkC, 2048,
        qtA, qtB, 2048, BIG, 128, 16, nullptr, nullptr, nullptr,
        nullptr, nullptr);
    // attention + fused pmean: scores = qt.prefix, softmax, w in-place, pmean
    attn2_kernel<<<4096, 256, 0, stream>>>(prefix, qtA, qtB, pmean);
    // attno[n, hs] = w[h][n] @ Wv[:, hs]
    gemmwv_kernel<<<256, 512, 0, stream>>>(qtA, qtB, wvT, attno);
    // TAIL: blocks 0-127: loss; blocks 128-255: out = (attno@Wo)*g
    gemm256<5><<<dim3(256), 512, SMEM, stream>>>(pmean, 2048, wrT, 2048,
        out, nullptr, 2048, BIG, 2048, 16, x, gbuf, lossA,
        attno, woT);

    finalize_loss_kernel<<<1, 64, 0, stream>>>(lossA, out + 8388608);
}